// Round 2
// baseline (369.805 us; speedup 1.0000x reference)
//
#include <hip/hip_runtime.h>

// NF4 dequant + batched GEMV: out[b,o] = sum_i x[b,i] * NF4[codes[o,i]] * absmax[o,i/64]
// x[8,4096] f32, codes[16384,4096] i32 (0..15), absmax[16384,64] f32 -> out[8,16384] f32
// HBM-bound: codes = 256 MiB -> floor ~43 us @ 6.3 TB/s.
//
// R2 design: 4 rows/wave, 4 waves/block, 1024 blocks (16 waves/CU target).
// - register double-buffered codes loads (prefetch next K-step across compute)
// - issue order [x(8), cr_next(4)] so vmcnt(4) wait leaves prefetch in flight
// - conflict-free LDS lut: lut2[c][64], lane i -> bank i%32 (2-way = free)
// - LDS gather reduction instead of 192-bpermute butterfly

#define IN_F   4096
#define OUT_F  16384
#define NBLK   64
#define ROWS   4
#define BATCH  8
#define WAVES  4
#define K_VEC  (IN_F / 4)     // 1024 int4/float4 per row
#define K_ITER (K_VEC / 64)   // 16 K-steps

__device__ __constant__ float NF4_CODE_C[16] = {
    -1.0f, -0.6961928009986877f, -0.5250730514526367f, -0.39491748809814453f,
    -0.28444138169288635f, -0.18477343022823334f, -0.09105003625154495f, 0.0f,
    0.07958029955625534f, 0.16093020141124725f, 0.24611230194568634f,
    0.33791524171829224f, 0.44070982933044434f, 0.5626170039176941f,
    0.7229568362236023f, 1.0f};

__global__ __launch_bounds__(256, 3) void nf4_gemv(
    const float* __restrict__ x,
    const int* __restrict__ codes,
    const float* __restrict__ absmax,
    float* __restrict__ out)
{
    __shared__ float lut2[16 * 64];          // 4 KiB, lut2[c*64+lane] = NF4[c]
    __shared__ float red[WAVES][32 * 64];    // 32 KiB reduction scratch

    for (int j = threadIdx.x; j < 16 * 64; j += 256)
        lut2[j] = NF4_CODE_C[j >> 6];
    __syncthreads();

    const int lane   = threadIdx.x & 63;
    const int wave   = threadIdx.x >> 6;
    const int o_base = (blockIdx.x * WAVES + wave) * ROWS;

    const int4*   codes4 = (const int4*)codes;
    const float4* x4     = (const float4*)x;

    // lane i holds absmax[o_base+r, i]  (NBLK == 64)
    float a_reg[ROWS];
#pragma unroll
    for (int r = 0; r < ROWS; ++r)
        a_reg[r] = absmax[(size_t)(o_base + r) * NBLK + lane];

    float acc[ROWS][BATCH];
#pragma unroll
    for (int r = 0; r < ROWS; ++r)
#pragma unroll
        for (int b = 0; b < BATCH; ++b) acc[r][b] = 0.0f;

    const int4* crow[ROWS];
#pragma unroll
    for (int r = 0; r < ROWS; ++r)
        crow[r] = codes4 + (size_t)(o_base + r) * K_VEC + lane;

    const float* lutl = lut2 + lane;  // lane-fixed bank

    // prologue: prefetch step 0 codes
    int4 crA[ROWS], crB[ROWS];
#pragma unroll
    for (int r = 0; r < ROWS; ++r) crA[r] = crow[r][0];

    float4 xv[BATCH];

#pragma unroll 1
    for (int i = 0; i < K_ITER / 2; ++i) {
        const int tA = 2 * i;
        const int tB = 2 * i + 1;

        // ---------- half A: compute step tA, prefetch step tB ----------
#pragma unroll
        for (int b = 0; b < BATCH; ++b)
            xv[b] = x4[b * K_VEC + tA * 64 + lane];
#pragma unroll
        for (int r = 0; r < ROWS; ++r)
            crB[r] = crow[r][tB * 64];

        {
            const int bi = tA * 4 + (lane >> 4);  // absmax block for this lane
#pragma unroll
            for (int r = 0; r < ROWS; ++r) {
                const float am = __shfl(a_reg[r], bi, 64);
                const float w0 = lutl[(crA[r].x & 15) << 6] * am;
                const float w1 = lutl[(crA[r].y & 15) << 6] * am;
                const float w2 = lutl[(crA[r].z & 15) << 6] * am;
                const float w3 = lutl[(crA[r].w & 15) << 6] * am;
#pragma unroll
                for (int b = 0; b < BATCH; ++b) {
                    float s = acc[r][b];
                    s = fmaf(w0, xv[b].x, s);
                    s = fmaf(w1, xv[b].y, s);
                    s = fmaf(w2, xv[b].z, s);
                    s = fmaf(w3, xv[b].w, s);
                    acc[r][b] = s;
                }
            }
        }

        // ---------- half B: compute step tB, prefetch step tB+1 ----------
#pragma unroll
        for (int b = 0; b < BATCH; ++b)
            xv[b] = x4[b * K_VEC + tB * 64 + lane];
        if (i < K_ITER / 2 - 1) {
#pragma unroll
            for (int r = 0; r < ROWS; ++r)
                crA[r] = crow[r][(tB + 1) * 64];
        }

        {
            const int bi = tB * 4 + (lane >> 4);
#pragma unroll
            for (int r = 0; r < ROWS; ++r) {
                const float am = __shfl(a_reg[r], bi, 64);
                const float w0 = lutl[(crB[r].x & 15) << 6] * am;
                const float w1 = lutl[(crB[r].y & 15) << 6] * am;
                const float w2 = lutl[(crB[r].z & 15) << 6] * am;
                const float w3 = lutl[(crB[r].w & 15) << 6] * am;
#pragma unroll
                for (int b = 0; b < BATCH; ++b) {
                    float s = acc[r][b];
                    s = fmaf(w0, xv[b].x, s);
                    s = fmaf(w1, xv[b].y, s);
                    s = fmaf(w2, xv[b].z, s);
                    s = fmaf(w3, xv[b].w, s);
                    acc[r][b] = s;
                }
            }
        }
    }

    // ---------- reduction: spill 32 partials/lane to LDS, gather conflict-free ----------
    float* myred = &red[wave][0];
#pragma unroll
    for (int r = 0; r < ROWS; ++r)
#pragma unroll
        for (int b = 0; b < BATCH; ++b)
            myred[(b * ROWS + r) * 64 + lane] = acc[r][b];  // bank = lane%32: free

    __asm__ volatile("s_waitcnt lgkmcnt(0)" ::: "memory");

    const int p = lane & 31;   // pair index: b = p>>2, r = p&3
    const int h = lane >> 5;   // half of the 64 partials
    float v = 0.0f;
#pragma unroll
    for (int j = 0; j < 32; ++j)
        v += myred[p * 64 + h * 32 + ((j + p) & 31)];  // rotated: bank=(p+j)%32, distinct per j
    v += __shfl_xor(v, 32, 64);

    if (lane < 32)
        out[(size_t)(p >> 2) * OUT_F + o_base + (p & 3)] = v;
}

extern "C" void kernel_launch(void* const* d_in, const int* in_sizes, int n_in,
                              void* d_out, int out_size, void* d_ws, size_t ws_size,
                              hipStream_t stream) {
    const float* x      = (const float*)d_in[0];
    const int*   codes  = (const int*)d_in[1];
    const float* absmax = (const float*)d_in[2];
    float*       out    = (float*)d_out;

    dim3 grid(OUT_F / (ROWS * WAVES));  // 1024 blocks
    dim3 block(256);
    nf4_gemv<<<grid, block, 0, stream>>>(x, codes, absmax, out);
}